// Round 1
// baseline (1892.394 us; speedup 1.0000x reference)
//
#include <hip/hip_runtime.h>

#define DIM   256
#define HW_   1024
#define NROWS 32768
#define KEMB  4096

// ---------------- ws layout ----------------
// [0,      131072)  int   idx[32768]
// [131072, 262144)  float S[32768]
// [262144, 278528)  float E[4096]
// [278528, 278536)  double loss_sum
#define WS_S_OFF    131072
#define WS_E_OFF    262144
#define WS_LOSS_OFF 278528

// ---------- K1: numpy-pairwise row sums of squares ----------
// Replicates numpy pairwise_sum for n=256: split 128+128; each 128-block uses
// 8 interleaved accumulators then ((r0+r1)+(r2+r3))+((r4+r5)+(r6+r7)).
// Products rounded separately from adds (no contraction), as np does
// tmp = zf*zf then np.sum(tmp).
__device__ __forceinline__ float np_sumsq_128(const float* q, int stride) {
#pragma clang fp contract(off)
  float r[8];
#pragma unroll
  for (int i = 0; i < 8; ++i) { float v = q[i * stride]; r[i] = v * v; }
  for (int blk = 8; blk < 128; blk += 8) {
#pragma unroll
    for (int i = 0; i < 8; ++i) {
      float v = q[(blk + i) * stride];
      float sq = v * v;
      r[i] = r[i] + sq;
    }
  }
  return ((r[0] + r[1]) + (r[2] + r[3])) + ((r[4] + r[5]) + (r[6] + r[7]));
}

__global__ __launch_bounds__(256) void norms_kernel(
    const float* __restrict__ z, const float* __restrict__ emb,
    float* __restrict__ S, float* __restrict__ E) {
#pragma clang fp contract(off)
  int t = blockIdx.x * 256 + threadIdx.x;
  if (t < NROWS) {
    // row n = b*1024 + hw ; element d at z[b*262144 + d*1024 + hw]
    int b = t >> 10, hw = t & 1023;
    const float* p = z + (size_t)b * (DIM * HW_) + hw;
    float s0 = np_sumsq_128(p, HW_);
    float s1 = np_sumsq_128(p + 128 * HW_, HW_);
    S[t] = s0 + s1;
  } else if (t < NROWS + KEMB) {
    int j = t - NROWS;
    const float* p = emb + (size_t)j * DIM;
    float s0 = np_sumsq_128(p, 1);
    float s1 = np_sumsq_128(p + 128, 1);
    E[j] = s0 + s1;
  }
}

// ---------- K2: tiled distance GEMM + streaming argmin ----------
// Block: 64 rows x (all 4096 embs in 64-wide tiles). 256 threads = 16 tj x 16 tr,
// each thread owns a 4x4 (row x emb) microtile. Dot products are sequential
// fp32 FMA chains over k ascending (BLAS sgemm microkernel order).
#define RT 64
#define JT 64
#define KC 64
#define PAD 68   // 16B-aligned row stride in floats

__global__ __launch_bounds__(256) void dist_argmin_kernel(
    const float* __restrict__ z, const float* __restrict__ emb,
    const float* __restrict__ S, const float* __restrict__ E,
    int* __restrict__ idx_out, float* __restrict__ idxf_out) {
  __shared__ float zt[RT * PAD];
  __shared__ float et[JT * PAD];
  __shared__ float rd[RT][17];
  __shared__ int   rj[RT][17];

  const int t  = threadIdx.x;
  const int tj = t & 15;
  const int tr = t >> 4;
  const int nb = blockIdx.x * RT;
  const int b  = nb >> 10;
  const int hwb = nb & 1023;               // 64 | 1024 so rows never straddle b
  const float* zb = z + (size_t)b * (DIM * HW_) + hwb;

  float bestd[4];
  int   bestj[4];
#pragma unroll
  for (int i = 0; i < 4; ++i) { bestd[i] = 3.0e38f; bestj[i] = 0; }

  float Sreg[4];
#pragma unroll
  for (int rr = 0; rr < 4; ++rr) Sreg[rr] = S[nb + tr * 4 + rr];

  for (int tile = 0; tile < KEMB / JT; ++tile) {
    const int jb = tile * JT;
    float acc[4][4];
#pragma unroll
    for (int a = 0; a < 4; ++a)
#pragma unroll
      for (int c = 0; c < 4; ++c) acc[a][c] = 0.0f;

    for (int kc = 0; kc < DIM / KC; ++kc) {
      const int kb = kc * KC;
      __syncthreads();
      // stage z tile [r][k] : global reads coalesced across r (w-contiguous)
#pragma unroll
      for (int i = 0; i < 4; ++i) {
        int flat = t + i * 256;     // 1024 float4 slots
        int r  = flat & 63;
        int k4 = flat >> 6;         // 0..15
        float4 v;
        v.x = zb[(size_t)(kb + k4 * 4 + 0) * HW_ + r];
        v.y = zb[(size_t)(kb + k4 * 4 + 1) * HW_ + r];
        v.z = zb[(size_t)(kb + k4 * 4 + 2) * HW_ + r];
        v.w = zb[(size_t)(kb + k4 * 4 + 3) * HW_ + r];
        *(float4*)&zt[r * PAD + k4 * 4] = v;
      }
      // stage e tile [j][k] : rows contiguous in k -> float4 coalesced
#pragma unroll
      for (int i = 0; i < 4; ++i) {
        int flat = t + i * 256;
        int k4 = flat & 15;
        int j  = flat >> 4;
        float4 v = *(const float4*)&emb[(size_t)(jb + j) * DIM + kb + k4 * 4];
        *(float4*)&et[j * PAD + k4 * 4] = v;
      }
      __syncthreads();
      // sequential-k FMA chains (k ascending within and across chunks)
      for (int k = 0; k < KC; k += 4) {
        float4 zf[4], ef[4];
#pragma unroll
        for (int rr = 0; rr < 4; ++rr)
          zf[rr] = *(const float4*)&zt[(tr * 4 + rr) * PAD + k];
#pragma unroll
        for (int jj = 0; jj < 4; ++jj)
          ef[jj] = *(const float4*)&et[(tj * 4 + jj) * PAD + k];
#pragma unroll
        for (int rr = 0; rr < 4; ++rr)
#pragma unroll
          for (int jj = 0; jj < 4; ++jj) {
            float a = acc[rr][jj];
            a = fmaf(zf[rr].x, ef[jj].x, a);
            a = fmaf(zf[rr].y, ef[jj].y, a);
            a = fmaf(zf[rr].z, ef[jj].z, a);
            a = fmaf(zf[rr].w, ef[jj].w, a);
            acc[rr][jj] = a;
          }
      }
    }
    // d = fl( fl(S+E) - 2*M ); 2*M exact, so fmaf(-2,M,A) == fl(A - fl(2M))
    float Ereg[4];
#pragma unroll
    for (int jj = 0; jj < 4; ++jj) Ereg[jj] = E[jb + tj * 4 + jj];
#pragma unroll
    for (int rr = 0; rr < 4; ++rr)
#pragma unroll
      for (int jj = 0; jj < 4; ++jj) {
        float A = Sreg[rr] + Ereg[jj];
        float d = fmaf(-2.0f, acc[rr][jj], A);
        int j = jb + tj * 4 + jj;             // strictly ascending per thread
        if (d < bestd[rr]) { bestd[rr] = d; bestj[rr] = j; }
      }
  }

  // cross-thread argmin: lexicographic (d, j) min == np.argmin first-occurrence
#pragma unroll
  for (int rr = 0; rr < 4; ++rr) {
    rd[tr * 4 + rr][tj] = bestd[rr];
    rj[tr * 4 + rr][tj] = bestj[rr];
  }
  __syncthreads();
  if (t < RT) {
    float bd = rd[t][0];
    int   bj = rj[t][0];
#pragma unroll
    for (int c = 1; c < 16; ++c) {
      float d2 = rd[t][c];
      int   j2 = rj[t][c];
      if (d2 < bd || (d2 == bd && j2 < bj)) { bd = d2; bj = j2; }
    }
    idx_out[nb + t]  = bj;
    idxf_out[nb + t] = (float)bj;
  }
}

// ---------- K3: gather + STE output + loss partial sums ----------
__global__ __launch_bounds__(256) void epilogue_kernel(
    const float* __restrict__ z, const float* __restrict__ emb,
    const int* __restrict__ idx, float* __restrict__ out0,
    double* __restrict__ loss_sum) {
#pragma clang fp contract(off)
  __shared__ double wsum[4];
  int gid = blockIdx.x * 256 + threadIdx.x;   // NCHW flat
  int hw = gid & 1023;
  int d  = (gid >> 10) & 255;
  int b  = gid >> 18;
  int n  = b * 1024 + hw;
  float zp = z[gid];
  float zq = emb[(size_t)idx[n] * DIM + d];
  float t  = zq - zp;                 // fl(z_q - zp)
  out0[gid] = zp + t;                 // fl(zp + fl(z_q - zp))  (STE)
  float sq = t * t;
  double acc = (double)sq;
#pragma unroll
  for (int off = 32; off > 0; off >>= 1) acc += __shfl_down(acc, off, 64);
  int lane = threadIdx.x & 63, wv = threadIdx.x >> 6;
  if (lane == 0) wsum[wv] = acc;
  __syncthreads();
  if (threadIdx.x == 0) {
    double bsum = (wsum[0] + wsum[1]) + (wsum[2] + wsum[3]);
    atomicAdd(loss_sum, bsum);
  }
}

// ---------- K4: finalize loss ----------
__global__ void finalize_loss(const double* __restrict__ loss_sum,
                              float* __restrict__ out_loss) {
  double m = loss_sum[0] / 8388608.0;
  float mf = (float)m;
  float bb = 10.0f * mf;        // fl(BETA * m)
  out_loss[0] = mf + bb;        // fl(m + fl(BETA*m))
}

extern "C" void kernel_launch(void* const* d_in, const int* in_sizes, int n_in,
                              void* d_out, int out_size, void* d_ws, size_t ws_size,
                              hipStream_t stream) {
  const float* z   = (const float*)d_in[0];
  const float* emb = (const float*)d_in[1];
  float* out = (float*)d_out;
  char* ws = (char*)d_ws;
  int*    idx = (int*)ws;
  float*  S   = (float*)(ws + WS_S_OFF);
  float*  E   = (float*)(ws + WS_E_OFF);
  double* ls  = (double*)(ws + WS_LOSS_OFF);

  hipMemsetAsync(ls, 0, sizeof(double), stream);

  // K1: 32768 S rows + 4096 E rows = 36864 threads
  norms_kernel<<<144, 256, 0, stream>>>(z, emb, S, E);

  // K2: 512 blocks of 64 rows
  dist_argmin_kernel<<<NROWS / RT, 256, 0, stream>>>(z, emb, S, E, idx,
                                                     out + 8388609);

  // K3: one thread per output element (8388608)
  epilogue_kernel<<<8388608 / 256, 256, 0, stream>>>(z, emb, idx, out, ls);

  // K4: loss scalar
  finalize_loss<<<1, 1, 0, stream>>>(ls, out + 8388608);
}

// Round 2
// 1258.762 us; speedup vs baseline: 1.5034x; 1.5034x over previous
//
#include <hip/hip_runtime.h>

#define DIM   256
#define HW_   1024
#define NROWS 32768
#define KEMB  4096

// ---------------- ws layout ----------------
#define WS_S_OFF    131072
#define WS_E_OFF    262144
#define WS_LOSS_OFF 278528

// ---------- K1: numpy-pairwise row sums of squares ----------
__device__ __forceinline__ float np_sumsq_128(const float* q, int stride) {
#pragma clang fp contract(off)
  float r[8];
#pragma unroll
  for (int i = 0; i < 8; ++i) { float v = q[i * stride]; r[i] = v * v; }
  for (int blk = 8; blk < 128; blk += 8) {
#pragma unroll
    for (int i = 0; i < 8; ++i) {
      float v = q[(blk + i) * stride];
      float sq = v * v;
      r[i] = r[i] + sq;
    }
  }
  return ((r[0] + r[1]) + (r[2] + r[3])) + ((r[4] + r[5]) + (r[6] + r[7]));
}

__global__ __launch_bounds__(256) void norms_kernel(
    const float* __restrict__ z, const float* __restrict__ emb,
    float* __restrict__ S, float* __restrict__ E) {
#pragma clang fp contract(off)
  int t = blockIdx.x * 256 + threadIdx.x;
  if (t < NROWS) {
    int b = t >> 10, hw = t & 1023;
    const float* p = z + (size_t)b * (DIM * HW_) + hw;
    float s0 = np_sumsq_128(p, HW_);
    float s1 = np_sumsq_128(p + 128 * HW_, HW_);
    S[t] = s0 + s1;
  } else if (t < NROWS + KEMB) {
    int j = t - NROWS;
    const float* p = emb + (size_t)j * DIM;
    float s0 = np_sumsq_128(p, 1);
    float s1 = np_sumsq_128(p + 128, 1);
    E[j] = s0 + s1;
  }
}

// ---------- K2: distance GEMM + streaming argmin ----------
// Block: 64 rows (z resident, all K in LDS) x full 4096-j sweep in 256-j tiles.
// 256 threads: g = t&31 (j-group), tr = t>>5 (row-group). 8x8 microtile.
// LDS k-major: zt[k][r] (broadcast reads), et[kk][j] (b64 reads, 8B lane
// stride -> 2-way aliasing = free). Total LDS 80 KB -> 2 blocks/CU.
#define RT 64
#define JT 256
#define KC 16

__global__ __launch_bounds__(256, 2) void dist_argmin_kernel(
    const float* __restrict__ z, const float* __restrict__ emb,
    const float* __restrict__ S, const float* __restrict__ E,
    int* __restrict__ idx_out, float* __restrict__ idxf_out) {
  __shared__ float zt[DIM * RT];   // 64 KB  zt[k*64 + r]
  __shared__ float et[KC * JT];    // 16 KB  et[kk*256 + j]

  const int t  = threadIdx.x;
  const int g  = t & 31;
  const int tr = t >> 5;
  const int nb = blockIdx.x * RT;
  const int b  = nb >> 10;
  const int hwb = nb & 1023;                  // 64 | 1024: rows never straddle b
  const float* zb = z + (size_t)b * (DIM * HW_) + hwb;

  // ---- stage z tile once: zt[k][r] (direct copy, z global is r-contiguous)
#pragma unroll
  for (int i = 0; i < 16; ++i) {
    int flat = t + i * 256;                   // 0..4095 float4 chunks
    int k  = flat >> 4;
    int r4 = flat & 15;
    float4 v = *(const float4*)(zb + (size_t)k * HW_ + r4 * 4);
    *(float4*)(zt + flat * 4) = v;
  }

  float bestd[8];
  int   bestj[8];
#pragma unroll
  for (int i = 0; i < 8; ++i) { bestd[i] = 3.0e38f; bestj[i] = 0; }

  float Sreg[8];
#pragma unroll
  for (int rr = 0; rr < 8; ++rr) Sreg[rr] = S[nb + tr * 8 + rr];

  // ---- register prefetch of first e chunk (jt=0, kc=0) ----
  // chunk cid = q*256 + t : j = cid>>2 (0..255), k4 = cid&3
  float4 pf[4];
#pragma unroll
  for (int q = 0; q < 4; ++q) {
    int cid = q * 256 + t;
    pf[q] = *(const float4*)(emb + (size_t)(cid >> 2) * DIM + (cid & 3) * 4);
  }

  for (int jt = 0; jt < KEMB / JT; ++jt) {
    float acc[8][8];
#pragma unroll
    for (int rr = 0; rr < 8; ++rr)
#pragma unroll
      for (int c = 0; c < 8; ++c) acc[rr][c] = 0.0f;

    for (int kc = 0; kc < DIM / KC; ++kc) {
      __syncthreads();                        // readers of previous et done
      // store prefetched chunk, transposed to k-major
#pragma unroll
      for (int q = 0; q < 4; ++q) {
        int cid = q * 256 + t;
        int j = cid >> 2, k4 = cid & 3;
        et[(k4 * 4 + 0) * JT + j] = pf[q].x;
        et[(k4 * 4 + 1) * JT + j] = pf[q].y;
        et[(k4 * 4 + 2) * JT + j] = pf[q].z;
        et[(k4 * 4 + 3) * JT + j] = pf[q].w;
      }
      // prefetch next stage (latency hidden behind compute below)
      int s = jt * (DIM / KC) + kc + 1;
      if (s < (KEMB / JT) * (DIM / KC)) {
        int njt = s >> 4, nkc = s & 15;
        const float* base = emb + (size_t)njt * JT * DIM + nkc * KC;
#pragma unroll
        for (int q = 0; q < 4; ++q) {
          int cid = q * 256 + t;
          pf[q] = *(const float4*)(base + (size_t)(cid >> 2) * DIM + (cid & 3) * 4);
        }
      }
      __syncthreads();
      // ---- compute: 16 ks, 8x8 FMAs each; k ascending (exact np order)
      const float* ztk = zt + (kc * KC) * RT;
#pragma unroll
      for (int kk = 0; kk < KC; ++kk) {
        float4 z0 = *(const float4*)(ztk + kk * RT + tr * 8);
        float4 z1 = *(const float4*)(ztk + kk * RT + tr * 8 + 4);
        float2 e0 = *(const float2*)(et + kk * JT + g * 2);
        float2 e1 = *(const float2*)(et + kk * JT + 64 + g * 2);
        float2 e2 = *(const float2*)(et + kk * JT + 128 + g * 2);
        float2 e3 = *(const float2*)(et + kk * JT + 192 + g * 2);
        float zr[8] = {z0.x, z0.y, z0.z, z0.w, z1.x, z1.y, z1.z, z1.w};
        float ev[8] = {e0.x, e0.y, e1.x, e1.y, e2.x, e2.y, e3.x, e3.y};
#pragma unroll
        for (int rr = 0; rr < 8; ++rr)
#pragma unroll
          for (int c = 0; c < 8; ++c)
            acc[rr][c] = fmaf(zr[rr], ev[c], acc[rr][c]);
      }
    }
    // ---- epilogue for this jtile: d = fl(fl(S+E) - 2M), lexicographic min
    int jb = jt * JT;
    float Ereg[8];
#pragma unroll
    for (int c = 0; c < 8; ++c)
      Ereg[c] = E[jb + (c >> 1) * 64 + g * 2 + (c & 1)];
#pragma unroll
    for (int rr = 0; rr < 8; ++rr)
#pragma unroll
      for (int c = 0; c < 8; ++c) {
        float A = Sreg[rr] + Ereg[c];
        float d = fmaf(-2.0f, acc[rr][c], A);
        int j = jb + (c >> 1) * 64 + g * 2 + (c & 1);
        if (d < bestd[rr] || (d == bestd[rr] && j < bestj[rr])) {
          bestd[rr] = d; bestj[rr] = j;
        }
      }
  }

  // ---- cross-thread argmin (reuse et space: 2048 floats + 2048 ints)
  __syncthreads();
  float* rd = et;
  int*   rj = (int*)(et + 2048);
#pragma unroll
  for (int rr = 0; rr < 8; ++rr) {
    rd[(tr * 8 + rr) * 32 + g] = bestd[rr];
    rj[(tr * 8 + rr) * 32 + g] = bestj[rr];
  }
  __syncthreads();
  if (t < RT) {
    float bd = rd[t * 32];
    int   bj = rj[t * 32];
    for (int c = 1; c < 32; ++c) {
      float d2 = rd[t * 32 + c];
      int   j2 = rj[t * 32 + c];
      if (d2 < bd || (d2 == bd && j2 < bj)) { bd = d2; bj = j2; }
    }
    idx_out[nb + t]  = bj;
    idxf_out[nb + t] = (float)bj;
  }
}

// ---------- K3: gather + STE output + loss partials (grid-stride, float4) ----------
__global__ __launch_bounds__(256) void epilogue_kernel(
    const float* __restrict__ z, const float* __restrict__ emb,
    const int* __restrict__ idx, float* __restrict__ out0,
    double* __restrict__ loss_sum) {
#pragma clang fp contract(off)
  __shared__ double wsum[4];
  double acc = 0.0;
#pragma unroll
  for (int it = 0; it < 4; ++it) {
    int u = (it * 2048 + blockIdx.x) * 256 + threadIdx.x;  // float4 index
    int gid = u * 4;
    int hw = gid & 1023;
    int d  = (gid >> 10) & 255;
    int b  = gid >> 18;
    int n  = b * 1024 + hw;
    float4 zp = *(const float4*)(z + gid);
    int4 iv = *(const int4*)(idx + n);
    float q0 = emb[(size_t)iv.x * DIM + d];
    float q1 = emb[(size_t)iv.y * DIM + d];
    float q2 = emb[(size_t)iv.z * DIM + d];
    float q3 = emb[(size_t)iv.w * DIM + d];
    float t0 = q0 - zp.x, t1 = q1 - zp.y, t2 = q2 - zp.z, t3 = q3 - zp.w;
    float4 o; o.x = zp.x + t0; o.y = zp.y + t1; o.z = zp.z + t2; o.w = zp.w + t3;
    *(float4*)(out0 + gid) = o;
    acc += (double)(t0 * t0);
    acc += (double)(t1 * t1);
    acc += (double)(t2 * t2);
    acc += (double)(t3 * t3);
  }
#pragma unroll
  for (int off = 32; off > 0; off >>= 1) acc += __shfl_down(acc, off, 64);
  int lane = threadIdx.x & 63, wv = threadIdx.x >> 6;
  if (lane == 0) wsum[wv] = acc;
  __syncthreads();
  if (threadIdx.x == 0) {
    double bsum = (wsum[0] + wsum[1]) + (wsum[2] + wsum[3]);
    atomicAdd(loss_sum, bsum);
  }
}

// ---------- K4: finalize loss ----------
__global__ void finalize_loss(const double* __restrict__ loss_sum,
                              float* __restrict__ out_loss) {
  double m = loss_sum[0] / 8388608.0;
  float mf = (float)m;
  float bb = 10.0f * mf;
  out_loss[0] = mf + bb;
}

extern "C" void kernel_launch(void* const* d_in, const int* in_sizes, int n_in,
                              void* d_out, int out_size, void* d_ws, size_t ws_size,
                              hipStream_t stream) {
  const float* z   = (const float*)d_in[0];
  const float* emb = (const float*)d_in[1];
  float* out = (float*)d_out;
  char* ws = (char*)d_ws;
  int*    idx = (int*)ws;
  float*  S   = (float*)(ws + WS_S_OFF);
  float*  E   = (float*)(ws + WS_E_OFF);
  double* ls  = (double*)(ws + WS_LOSS_OFF);

  hipMemsetAsync(ls, 0, sizeof(double), stream);

  norms_kernel<<<144, 256, 0, stream>>>(z, emb, S, E);

  dist_argmin_kernel<<<NROWS / RT, 256, 0, stream>>>(z, emb, S, E, idx,
                                                     out + 8388609);

  epilogue_kernel<<<2048, 256, 0, stream>>>(z, emb, idx, out, ls);

  finalize_loss<<<1, 1, 0, stream>>>(ls, out + 8388608);
}